// Round 4
// baseline (830.616 us; speedup 1.0000x reference)
//
#include <hip/hip_runtime.h>
#include <stdint.h>

#define E_EDGES 262144
#define TILE_M 128
#define NBLK (E_EDGES / TILE_M)      // 2048 blocks, natural edge order

typedef unsigned short ushort_t;
typedef __attribute__((ext_vector_type(8))) short short8;
typedef __attribute__((ext_vector_type(4))) float f32x4;

// ---- workspace layout (bytes) ----
#define OFF_WT   0                              // bf16 Wt[n=256][k=512] (transposed combined W1;W2)
#define OFF_WP   (512*256*2)                    // bf16 Wpf2[s=8][pair=16][lane=64][jj=8] all-pairs GEMM2 frags
#define OFF_HIST (OFF_WP + 8*16*64*8*2)         // int[16] per-pair counts
#define OFF_SUMS (OFF_HIST + 64)                // float[16] per-pair loss sums

__device__ __forceinline__ ushort_t f2bf(float f) {
  union { float f; unsigned u; } c; c.f = f;
  unsigned r = c.u + 0x7fffu + ((c.u >> 16) & 1u);   // RNE, finite inputs
  return (ushort_t)(r >> 16);
}

__device__ __forceinline__ unsigned cvtpk_bf16(float lo, float hi) {
  unsigned r;
  asm("v_cvt_pk_bf16_f32 %0, %1, %2" : "=v"(r) : "v"(lo), "v"(hi));
  return r;                                        // [lo16]=bf16(lo), [hi16]=bf16(hi)
}

__device__ __forceinline__ void async_copy16(void* lds, const void* g) {
  __builtin_amdgcn_global_load_lds(
      (const __attribute__((address_space(1))) unsigned int*)g,
      (__attribute__((address_space(3))) unsigned int*)lds, 16, 0, 0);
}

// ---- prologue: bf16 Wt (transposed), all-pairs W_pred fragments, zero hist/sums ----
__global__ __launch_bounds__(256) void prep_k(const float* __restrict__ W1,
    const float* __restrict__ W2, const float* __restrict__ Wp,
    char* __restrict__ ws) {
  const int i = blockIdx.x * 256 + threadIdx.x;
  if (i < 512 * 256) {            // Wt[n][k] = (k<256 ? W1[k][n] : W2[k-256][n])
    ushort_t* Wt = (ushort_t*)(ws + OFF_WT);
    const int n = i >> 9, k = i & 511;
    const float v = (k < 256) ? W1[(k << 8) + n] : W2[((k - 256) << 8) + n];
    Wt[i] = f2bf(v);
  }
  if (i < 8 * 16 * 64 * 8) {      // Wpf2[s][p][lane][jj] = W_pred[p][s*32+8*(lane>>4)+jj][lane&15]
    ushort_t* Wpf = (ushort_t*)(ws + OFF_WP);
    const int jj = i & 7, l = (i >> 3) & 63, p = (i >> 9) & 15, s = i >> 13;
    const int k = s * 32 + (l >> 4) * 8 + jj, c = l & 15;
    Wpf[i] = f2bf(Wp[((p << 8) + k) * 16 + c]);
  }
  if (i < 16) {
    ((int*)(ws + OFF_HIST))[i] = 0;
    ((float*)(ws + OFF_SUMS))[i] = 0.f;
  }
}

// ---- fused main kernel ----
// K-loop: A staged fp32 via global_load_lds (3 rotating bufs, issued 2 stages
// ahead, XOR-chunk-swizzled via pre-swizzled GLOBAL source); B direct L2->regs
// (1 stage ahead). Per stage: issue B(kt+1), issue A(kt+2), MFMA(kt),
// s_waitcnt vmcnt(2), s_barrier. No ds_write, no lgkm drain at the barrier.
__global__ __launch_bounds__(512, 4) void main_k(
    const float* __restrict__ h_src, const float* __restrict__ h_dst,
    const float* __restrict__ b_dec, const float* __restrict__ b_pred,
    const int* __restrict__ st, const int* __restrict__ dt,
    const int* __restrict__ etc_arr, const int* __restrict__ emap,
    char* __restrict__ ws) {
  const ushort_t* Wt = (const ushort_t*)(ws + OFF_WT);
  const short8* Wpf2 = (const short8*)(ws + OFF_WP);
  int* hist = (int*)(ws + OFF_HIST);
  float* sums = (float*)(ws + OFF_SUMS);

  const int tb = blockIdx.x * TILE_M;

  __shared__ __align__(16) char smem[65536];
  __shared__ float lsums[16];
  __shared__ int lcnts[16];
  // A staging: 3 bufs x 16KB fp32 [128 rows][8 chunks of 16B], chunk-swizzled.
  // H (64KB) overlays the staging after the K-loop.
  char* const A_buf0 = smem;
  char* const A_buf1 = smem + 16384;
  char* const A_buf2 = smem + 32768;
  ushort_t* H_ls = (ushort_t*)smem;                // [128][256] bf16, XOR-swizzled chunks

  const int t = threadIdx.x;
  const int w = t >> 6, lane = t & 63;
  const int quad = lane >> 4, l15 = lane & 15;
  const int wm = w >> 2, wn = w & 3;  // wave tile: rows 64*wm, cols 64*wn

  if (t < 16) { lsums[t] = 0.f; lcnts[t] = 0; }

  const f32x4 zero4 = {0.f, 0.f, 0.f, 0.f};
  f32x4 acc[4][4];
#pragma unroll
  for (int i = 0; i < 4; ++i)
#pragma unroll
    for (int j = 0; j < 4; ++j) acc[i][j] = zero4;

  // ---- helpers (FIXED VMEM op counts: 2 asyncs / 4 loads) ----
  // stage_A: thread t covers rows (t>>3) and 64+(t>>3); LDS[r][c] = G[r][c^(r&7)]
  const int srow = t >> 3;
  const int scol = ((t & 7) ^ (srow & 7)) * 4;     // pre-swizzled source chunk (floats)
  auto stage_A = [&](int kt, char* buf) {          // 2 async ops
    const float* srcb = (kt < 8) ? h_src : h_dst;
    const int kof = (kt & 7) * 32;
    async_copy16(buf + t * 16,
                 srcb + ((size_t)(tb + srow) << 8) + kof + scol);
    async_copy16(buf + 8192 + t * 16,
                 srcb + ((size_t)(tb + 64 + srow) << 8) + kof + scol);
  };
  auto load_B = [&](int kt, short8* breg) {        // 4 global loads (L2-hot Wt)
#pragma unroll
    for (int j = 0; j < 4; ++j)
      breg[j] = *(const short8*)(Wt + (wn * 64 + j * 16 + l15) * 512 + kt * 32 + quad * 8);
  };
  const int c_lo = ((quad * 2) ^ (l15 & 7)) * 16;      // lane-const swizzled chunk offsets
  const int c_hi = ((quad * 2 + 1) ^ (l15 & 7)) * 16;
  auto mma_stage = [&](const char* Ab, const short8* breg) {
    short8 a[4];
#pragma unroll
    for (int i = 0; i < 4; ++i) {
      const int rbase = (wm * 64 + i * 16 + l15) * 128;
      const f32x4 lo = *(const f32x4*)(Ab + rbase + c_lo);
      const f32x4 hi = *(const f32x4*)(Ab + rbase + c_hi);
      union { unsigned u[4]; short8 v; } pk;
      pk.u[0] = cvtpk_bf16(lo[0], lo[1]);
      pk.u[1] = cvtpk_bf16(lo[2], lo[3]);
      pk.u[2] = cvtpk_bf16(hi[0], hi[1]);
      pk.u[3] = cvtpk_bf16(hi[2], hi[3]);
      a[i] = pk.v;
    }
#pragma unroll
    for (int j = 0; j < 4; ++j)
#pragma unroll
      for (int i = 0; i < 4; ++i)
        acc[i][j] = __builtin_amdgcn_mfma_f32_16x16x32_bf16(a[i], breg[j], acc[i][j], 0, 0, 0);
  };

  short8 breg[2][4];
  char* const Abuf[3] = {A_buf0, A_buf1, A_buf2};

  // ---- prologue: queue [A(0)x2, B(0)x4, A(1)x2]; wait A0+B0; barrier ----
  stage_A(0, A_buf0);
  __builtin_amdgcn_sched_barrier(0);
  load_B(0, breg[0]);
  __builtin_amdgcn_sched_barrier(0);
  stage_A(1, A_buf1);
  __builtin_amdgcn_sched_barrier(0);
  asm volatile("s_waitcnt vmcnt(2)" ::: "memory");  // A(0),B(0) done; A(1) in flight
  __builtin_amdgcn_s_barrier();
  __builtin_amdgcn_sched_barrier(0);

  // ---- steady state: kt = 0..13 ----
#pragma unroll
  for (int kt = 0; kt < 14; ++kt) {
    load_B(kt + 1, breg[(kt + 1) & 1]);            // queue: [A(kt+1)x2, B(kt+1)x4]
    __builtin_amdgcn_sched_barrier(0);
    stage_A(kt + 2, Abuf[(kt + 2) % 3]);           // queue: [... , A(kt+2)x2]
    __builtin_amdgcn_sched_barrier(0);
    mma_stage(Abuf[kt % 3], breg[kt & 1]);
    asm volatile("s_waitcnt vmcnt(2)" ::: "memory");  // A(kt+1)+B(kt+1) done; A(kt+2) in flight
    __builtin_amdgcn_s_barrier();
    __builtin_amdgcn_sched_barrier(0);
  }
  // ---- kt = 14 (no A(16) prefetch) ----
  load_B(15, breg[1]);
  __builtin_amdgcn_sched_barrier(0);
  mma_stage(A_buf2, breg[0]);                      // 14 % 3 == 2
  asm volatile("s_waitcnt vmcnt(0)" ::: "memory"); // A(15)+B(15) done
  __builtin_amdgcn_s_barrier();
  __builtin_amdgcn_sched_barrier(0);
  // ---- kt = 15 ----
  mma_stage(A_buf0, breg[1]);                      // 15 % 3 == 0
  __syncthreads();                                 // all LDS reads drained; H overlays staging

  // epilogue GEMM1: bias + relu -> H_ls bf16, XOR-swizzled 16B chunks:
  // addr(row,col) = row*256 + ((col>>3 ^ (row&7))<<3) + (col&7)
  float bj[4];
#pragma unroll
  for (int j = 0; j < 4; ++j) bj[j] = b_dec[wn * 64 + j * 16 + l15];
#pragma unroll
  for (int i = 0; i < 4; ++i)
#pragma unroll
    for (int j = 0; j < 4; ++j)
#pragma unroll
      for (int r = 0; r < 4; ++r) {
        const int row = wm * 64 + i * 16 + quad * 4 + r;
        const int col = wn * 64 + j * 16 + l15;
        float v = acc[i][j][r] + bj[j];
        v = fmaxf(v, 0.f);
        H_ls[row * 256 + (((col >> 3) ^ (row & 7)) << 3) + (col & 7)] = f2bf(v);
      }
  __syncthreads();

  // GEMM2 all-pairs: M=128, N=256 (16 pairs x 16 classes), K=256.
  // Wave (wm,wn): rows [64wm,64wm+64), cols [64wn,64wn+64) = pairs [4wn,4wn+4).
  f32x4 acc2[4][4];
#pragma unroll
  for (int i = 0; i < 4; ++i)
#pragma unroll
    for (int j = 0; j < 4; ++j) acc2[i][j] = zero4;
#pragma unroll
  for (int s = 0; s < 8; ++s) {
    short8 a[4], b[4];
#pragma unroll
    for (int x = 0; x < 4; ++x) {
      const int row = wm * 64 + x * 16 + l15;
      a[x] = *(const short8*)(H_ls + row * 256 + (((s * 4 + quad) ^ (row & 7)) << 3));
    }
#pragma unroll
    for (int j = 0; j < 4; ++j)
      b[j] = Wpf2[(s * 16 + wn * 4 + j) * 64 + lane];   // L2-hot, shared by all blocks
#pragma unroll
    for (int x = 0; x < 4; ++x)
#pragma unroll
      for (int j = 0; j < 4; ++j)
        acc2[x][j] = __builtin_amdgcn_mfma_f32_16x16x32_bf16(a[x], b[j], acc2[x][j], 0, 0, 0);
  }

  // CE: one softmax per owned row; select the row's own pair block via cndmask.
  float bpj[4];
#pragma unroll
  for (int j = 0; j < 4; ++j) bpj[j] = b_pred[(wn * 4 + j) * 16 + l15];
  float wsum[4] = {0.f, 0.f, 0.f, 0.f};
  int wcnt[4] = {0, 0, 0, 0};
#pragma unroll
  for (int i = 0; i < 4; ++i)
#pragma unroll
    for (int r = 0; r < 4; ++r) {
      const int row = wm * 64 + i * 16 + quad * 4 + r;
      const int e = tb + row;
      const int pe = st[e] * 4 + dt[e];              // uniform across the 16-lane group
      float v = 0.f;
#pragma unroll
      for (int j = 0; j < 4; ++j) {
        const bool hit = (pe == wn * 4 + j);
        v = hit ? (acc2[i][j][r] + bpj[j]) : v;
      }
      float m = v;
#pragma unroll
      for (int o = 1; o < 16; o <<= 1) m = fmaxf(m, __shfl_xor(m, o, 16));
      float sm = __expf(v - m);
#pragma unroll
      for (int o = 1; o < 16; o <<= 1) sm += __shfl_xor(sm, o, 16);
      const int label = emap[pe * 24 + etc_arr[e]];
      const float vlab = __shfl(v, (lane & 48) + label, 64);
      const float loss = m + __logf(sm) - vlab;
#pragma unroll
      for (int j = 0; j < 4; ++j)
        if (pe == wn * 4 + j && l15 == 0) { wsum[j] += loss; wcnt[j] += 1; }
    }
  __syncthreads();   // lsums/lcnts zero-init visible
#pragma unroll
  for (int j = 0; j < 4; ++j) {
    float wv = wsum[j];
    int cv = wcnt[j];
    wv += __shfl_xor(wv, 16, 64);
    wv += __shfl_xor(wv, 32, 64);
    cv += __shfl_xor(cv, 16, 64);
    cv += __shfl_xor(cv, 32, 64);
    if (lane == 0 && cv > 0) {
      atomicAdd(&lsums[wn * 4 + j], wv);
      atomicAdd(&lcnts[wn * 4 + j], cv);
    }
  }
  __syncthreads();
  if (t < 16 && lcnts[t] > 0) {
    atomicAdd(&sums[t], lsums[t]);
    atomicAdd(&hist[t], lcnts[t]);
  }
}

__global__ void finalize_k(const char* __restrict__ ws, float* __restrict__ out) {
  const float* sums = (const float*)(ws + OFF_SUMS);
  const int* hist = (const int*)(ws + OFF_HIST);
  const int t = threadIdx.x;
  float g = 0.f, pr = 0.f;
  if (t < 16) {
    const int c = hist[t];
    if (c > 0) { g = sums[t] / (float)c; pr = 1.f; }
  }
#pragma unroll
  for (int o = 1; o < 16; o <<= 1) { g += __shfl_xor(g, o, 64); pr += __shfl_xor(pr, o, 64); }
  if (t == 0) out[0] = g / pr;
}

extern "C" void kernel_launch(void* const* d_in, const int* in_sizes, int n_in,
                              void* d_out, int out_size, void* d_ws, size_t ws_size,
                              hipStream_t stream) {
  const float* h_src  = (const float*)d_in[0];
  const float* h_dst  = (const float*)d_in[1];
  const float* W1     = (const float*)d_in[2];
  const float* W2     = (const float*)d_in[3];
  const float* b_dec  = (const float*)d_in[4];
  const float* W_pred = (const float*)d_in[5];
  const float* b_pred = (const float*)d_in[6];
  const int* st   = (const int*)d_in[7];
  const int* dt   = (const int*)d_in[8];
  const int* etc  = (const int*)d_in[9];
  const int* emap = (const int*)d_in[10];
  char* ws = (char*)d_ws;
  float* out = (float*)d_out;

  prep_k<<<512, 256, 0, stream>>>(W1, W2, W_pred, ws);
  main_k<<<NBLK, 512, 0, stream>>>(h_src, h_dst, b_dec, b_pred, st, dt, etc, emap, ws);
  finalize_k<<<1, 64, 0, stream>>>(ws, out);
}